// Round 11
// baseline (236.385 us; speedup 1.0000x reference)
//
#include <hip/hip_runtime.h>
#include <math.h>

// ProtoLoss, MI355X (gfx950) — hi-only f16 MFMA (K=192), R4-proven skeleton.
//
// reference:  anchor = mean(x[:,1:,:],1); pos = x[:,0,:]
//   logit[i,j] = -dist2 = s[i,j] + K_i,  s = 2*pos_i.anc_j + b_j,
//   b_j = -|anc_j|^2 + 2e*sum(anc_j).   K_i cancels in log_softmax/argmax.
//   nloss = mean(lse_i - s_ii), prec1 = 100*mean(argmax_j s == i).
//
// Precision: A = f16(2*log2e*pos), B = f16(anc), K=192 (hi-only).  The prior
// K=384 [hi|lo] concat computed only hihi+lolo (cross terms hilo+lohi were
// never present) and passed with absmax 0.0; lolo ~ 2^-22 is negligible vs
// the absent 2^-11 cross terms, so hi-only has the same error class at half
// the FLOPs.  Both outputs are means over 8192 rows (iid errors /90).
// R7/R9/R10 post-mortem: dbuf, occupancy, counted-vmcnt all <= R4's simple
// 2-barrier single-buffer structure — keep R4 skeleton, halve the work.

#define NROWS  8192
#define DDIM   192
#define KSPL   192            // hi-only
#define X3     576
#define FEPS   1e-6f
#define LOG2E  1.4426950408889634f
#define LN2    0.6931471805599453f

#define BM 128
#define BN 128
#define BK 64
#define NSPLIT 16
#define JRANGE 512            // NROWS / NSPLIT
#define JTILES 4              // JRANGE / BN
#define NPART  32             // NSPLIT * 2 (wn halves)
#define NCOMB  32             // combine-partial blocks

typedef _Float16 f16;
typedef _Float16 f16x4 __attribute__((ext_vector_type(4)));
typedef _Float16 f16x8 __attribute__((ext_vector_type(8)));
typedef float    f32x4 __attribute__((ext_vector_type(4)));

__device__ __forceinline__ void async_copy16(const void* g, void* l) {
  __builtin_amdgcn_global_load_lds(
      (const __attribute__((address_space(1))) unsigned int*)g,
      (__attribute__((address_space(3))) unsigned int*)l, 16, 0, 0);
}

// ---------- Kernel 1: x -> ph = f16(2*log2e*pos), ah = f16(anc), bvec -------
__global__ __launch_bounds__(256) void prep_kernel(const float* __restrict__ x,
                                                   f16* __restrict__ ph,
                                                   f16* __restrict__ ah,
                                                   float* __restrict__ bvec) {
  const int row  = (blockIdx.x * 256 + threadIdx.x) >> 6;
  const int lane = threadIdx.x & 63;
  float an = 0.f, as = 0.f;
  if (lane < 48) {
    const float* xr = x + (size_t)row * X3;
    const int d = lane * 4;
    const float4 p = *(const float4*)(xr + d);
    const float4 u = *(const float4*)(xr + DDIM + d);
    const float4 w = *(const float4*)(xr + 2 * DDIM + d);
    const float a0 = 0.5f * (u.x + w.x), a1 = 0.5f * (u.y + w.y);
    const float a2 = 0.5f * (u.z + w.z), a3 = 0.5f * (u.w + w.w);
    an = a0 * a0 + a1 * a1 + a2 * a2 + a3 * a3;
    as = a0 + a1 + a2 + a3;
    const float C2 = 2.0f * LOG2E;             // fold 2*log2e into A side
    f16x4 hv = {(f16)(p.x * C2), (f16)(p.y * C2), (f16)(p.z * C2), (f16)(p.w * C2)};
    *(f16x4*)(ph + (size_t)row * KSPL + d) = hv;
    f16x4 gv = {(f16)a0, (f16)a1, (f16)a2, (f16)a3};
    *(f16x4*)(ah + (size_t)row * KSPL + d) = gv;
  }
  #pragma unroll
  for (int m = 32; m; m >>= 1) {
    an += __shfl_xor(an, m);
    as += __shfl_xor(as, m);
  }
  if (lane == 0) bvec[row] = LOG2E * (-an + 2.0f * FEPS * as);  // log2-domain
}

// ---------- Kernel 2: f16 MFMA GEMM (K=192) + fused online LSE/argmax -------
// grid (64, 16) = 1024 blocks of 256 thr = 4 blocks/CU co-resident
// (32 KB LDS, <=128 VGPR via launch_bounds).  4 waves as 2x2; wave = 64x64
// via 4x4 frags of mfma_f32_16x16x32_f16.  Single-buffer LDS, R4-proven
// skeleton: [barrier; stage; barrier(drain); compute].
__global__ __launch_bounds__(256, 4) void main_kernel(
    const f16* __restrict__ Ag, const f16* __restrict__ Bg,
    const float* __restrict__ bvec,
    float* __restrict__ pm, float* __restrict__ ps, int* __restrict__ pa,
    float* __restrict__ diag) {
  __shared__ __align__(16) f16 As[BM * BK];   // 16 KB
  __shared__ __align__(16) f16 Bs[BN * BK];   // 16 KB
  const int tid  = threadIdx.x;
  const int lane = tid & 63;
  const int wid  = tid >> 6;
  const int wm = wid >> 1, wn = wid & 1;
  const int lLow = lane & 15, lHi = lane >> 4, l7 = lane & 7;
  const int i0 = blockIdx.x * BM;
  const int split = blockIdx.y;

  // staging: chunk ci = q*4+wid covers LDS rows [ci*8, ci*8+8); lane ->
  // (row = ci*8 + lane>>3, slot = lane&7); source k pre-swizzled so
  // LDS[row][slot] holds global k-chunk (slot ^ (row&7)).
  const int rsub = lane >> 3;
  const int srck = (l7 ^ rsub) * 8;

  float mrun[16], srun[16];
  int   arun[16];
  #pragma unroll
  for (int r = 0; r < 16; ++r) { mrun[r] = -3.0e38f; srun[r] = 0.f; arun[r] = 0; }

  for (int jt = 0; jt < JTILES; ++jt) {
    const int j0 = split * JRANGE + jt * BN;
    f32x4 acc[4][4];
    #pragma unroll
    for (int mf = 0; mf < 4; ++mf)
      #pragma unroll
      for (int nf = 0; nf < 4; ++nf) acc[mf][nf] = (f32x4)0.f;

    #pragma unroll
    for (int kc = 0; kc < KSPL; kc += BK) {
      __syncthreads();                 // previous tile fully consumed
      #pragma unroll
      for (int q = 0; q < 4; ++q) {
        const int ci  = q * 4 + wid;
        const int row = ci * 8 + rsub;
        async_copy16(Ag + (size_t)(i0 + row) * KSPL + kc + srck, (void*)(As + ci * 512));
        async_copy16(Bg + (size_t)(j0 + row) * KSPL + kc + srck, (void*)(Bs + ci * 512));
      }
      __syncthreads();                 // compiler drains vmcnt before barrier
      #pragma unroll
      for (int kk = 0; kk < 2; ++kk) {
        const int ksw = ((kk * 4 + lHi) ^ l7) * 8;  // swizzled read chunk
        f16x8 af[4];
        #pragma unroll
        for (int mf = 0; mf < 4; ++mf)
          af[mf] = *(const f16x8*)(As + (wm * 64 + mf * 16 + lLow) * 64 + ksw);
        #pragma unroll
        for (int nf = 0; nf < 4; ++nf) {
          f16x8 bf = *(const f16x8*)(Bs + (wn * 64 + nf * 16 + lLow) * 64 + ksw);
          #pragma unroll
          for (int mf = 0; mf < 4; ++mf)
            acc[mf][nf] = __builtin_amdgcn_mfma_f32_16x16x32_f16(af[mf], bf, acc[mf][nf], 0, 0, 0);
        }
      }
    }

    // ---- epilogue: fold this 128-wide j-tile into per-lane online state ----
    float bv[4];
    int   gc[4];
    #pragma unroll
    for (int nf = 0; nf < 4; ++nf) {
      gc[nf] = j0 + wn * 64 + nf * 16 + lLow;
      bv[nf] = bvec[gc[nf]];
    }
    // diagonal tile: j0 == i0  <=>  split*4 + jt == blockIdx.x
    const bool dtile = (split == (int)(blockIdx.x >> 2)) && (jt == (int)(blockIdx.x & 3));
    #pragma unroll
    for (int mf = 0; mf < 4; ++mf) {
      #pragma unroll
      for (int reg = 0; reg < 4; ++reg) {
        const int rs = mf * 4 + reg;
        const int grow = i0 + wm * 64 + mf * 16 + lHi * 4 + reg;
        float v0 = acc[mf][0][reg] + bv[0];   // log2-domain logits
        float v1 = acc[mf][1][reg] + bv[1];
        float v2 = acc[mf][2][reg] + bv[2];
        float v3 = acc[mf][3][reg] + bv[3];
        if (dtile) {
          if (grow == gc[0]) diag[grow] = v0;
          if (grow == gc[1]) diag[grow] = v1;
          if (grow == gc[2]) diag[grow] = v2;
          if (grow == gc[3]) diag[grow] = v3;
        }
        float tm = v0; int tj = gc[0];                // cols ascend with nf:
        if (v1 > tm) { tm = v1; tj = gc[1]; }         // strict > = first max
        if (v2 > tm) { tm = v2; tj = gc[2]; }
        if (v3 > tm) { tm = v3; tj = gc[3]; }
        float nm = fmaxf(tm, mrun[rs]);
        float se = exp2f(v0 - nm) + exp2f(v1 - nm) + exp2f(v2 - nm) + exp2f(v3 - nm);
        srun[rs] = srun[rs] * exp2f(mrun[rs] - nm) + se;
        if (tm > mrun[rs]) arun[rs] = tj;             // tie keeps earlier j
        mrun[rs] = nm;
      }
    }
  }

  // ---- reduce the 16 lanes sharing each row, write partials ----
  #pragma unroll
  for (int rs = 0; rs < 16; ++rs) {
    float mm = mrun[rs], ss = srun[rs];
    int aa = arun[rs];
    #pragma unroll
    for (int d = 1; d < 16; d <<= 1) {
      float om = __shfl_xor(mm, d, 16);
      float os = __shfl_xor(ss, d, 16);
      int   oa = __shfl_xor(aa, d, 16);
      float nm = fmaxf(mm, om);
      ss = ss * exp2f(mm - nm) + os * exp2f(om - nm);
      if (om > mm || (om == mm && oa < aa)) aa = oa;      // min-j on ties
      mm = nm;
    }
    if (lLow == 0) {
      const int grow = i0 + wm * 64 + (rs >> 2) * 16 + lHi * 4 + (rs & 3);
      const int sidx = split * 2 + wn;
      pm[(size_t)sidx * NROWS + grow] = mm;
      ps[(size_t)sidx * NROWS + grow] = ss;
      pa[(size_t)sidx * NROWS + grow] = aa;
    }
  }
}

// ---------- Kernel 3: merge partials per row (32 blocks, 1 row/thread) ------
__global__ __launch_bounds__(256) void combine_partial(
    const float* __restrict__ pm, const float* __restrict__ ps,
    const int* __restrict__ pa, const float* __restrict__ diag,
    float* __restrict__ partL, float* __restrict__ partC) {
  const int i = blockIdx.x * 256 + threadIdx.x;   // NCOMB*256 == NROWS
  float mm = pm[i];
  int   aa = pa[i];
  #pragma unroll
  for (int s = 1; s < NPART; ++s) {
    float om = pm[(size_t)s * NROWS + i];
    int   oa = pa[(size_t)s * NROWS + i];
    if (om > mm || (om == mm && oa < aa)) { mm = om; aa = oa; }
  }
  float ss = 0.f;
  #pragma unroll
  for (int s = 0; s < NPART; ++s)
    ss += ps[(size_t)s * NROWS + i] * exp2f(pm[(size_t)s * NROWS + i] - mm);
  float lsum = (mm + log2f(ss) - diag[i]) * LN2;  // back to nats
  float csum = (aa == i) ? 1.0f : 0.0f;
  #pragma unroll
  for (int d = 32; d; d >>= 1) {
    lsum += __shfl_xor(lsum, d);
    csum += __shfl_xor(csum, d);
  }
  __shared__ float wl[4], wc[4];
  int w = threadIdx.x >> 6;
  if ((threadIdx.x & 63) == 0) { wl[w] = lsum; wc[w] = csum; }
  __syncthreads();
  if (threadIdx.x == 0) {
    partL[blockIdx.x] = wl[0] + wl[1] + wl[2] + wl[3];
    partC[blockIdx.x] = wc[0] + wc[1] + wc[2] + wc[3];
  }
}

// ---------- Kernel 4: final scalars ----------
__global__ __launch_bounds__(64) void final_kernel(
    const float* __restrict__ partL, const float* __restrict__ partC,
    float* __restrict__ out) {
  int t = threadIdx.x;
  float l = (t < NCOMB) ? partL[t] : 0.f;
  float c = (t < NCOMB) ? partC[t] : 0.f;
  #pragma unroll
  for (int d = 32; d; d >>= 1) {
    l += __shfl_xor(l, d);
    c += __shfl_xor(c, d);
  }
  if (t == 0) {
    out[0] = l / (float)NROWS;
    out[1] = 100.f * c / (float)NROWS;
  }
}

extern "C" void kernel_launch(void* const* d_in, const int* in_sizes, int n_in,
                              void* d_out, int out_size, void* d_ws, size_t ws_size,
                              hipStream_t stream) {
  const float* x = (const float*)d_in[0];
  float* out = (float*)d_out;

  // workspace layout (~10.5 MB), 256B-aligned slices
  char* ws = (char*)d_ws;
  size_t off = 0;
  auto take = [&](size_t bytes) { void* p = ws + off; off += (bytes + 255) & ~(size_t)255; return p; };
  f16*   ph    = (f16*)take((size_t)NROWS * KSPL * sizeof(f16));
  f16*   ah    = (f16*)take((size_t)NROWS * KSPL * sizeof(f16));
  float* bvec  = (float*)take((size_t)NROWS * sizeof(float));
  float* pm    = (float*)take((size_t)NPART * NROWS * sizeof(float));
  float* ps    = (float*)take((size_t)NPART * NROWS * sizeof(float));
  int*   pa    = (int*)take((size_t)NPART * NROWS * sizeof(int));
  float* diag  = (float*)take((size_t)NROWS * sizeof(float));
  float* partL = (float*)take((size_t)NCOMB * sizeof(float));
  float* partC = (float*)take((size_t)NCOMB * sizeof(float));

  prep_kernel<<<dim3((NROWS * 64) / 256), 256, 0, stream>>>(x, ph, ah, bvec);
  main_kernel<<<dim3(NROWS / BM, NSPLIT), 256, 0, stream>>>(ph, ah, bvec, pm, ps, pa, diag);
  combine_partial<<<dim3(NCOMB), 256, 0, stream>>>(pm, ps, pa, diag, partL, partC);
  final_kernel<<<1, 64, 0, stream>>>(partL, partC, out);
}

// Round 12
// 166.696 us; speedup vs baseline: 1.4181x; 1.4181x over previous
//
#include <hip/hip_runtime.h>
#include <math.h>

// ProtoLoss, MI355X (gfx950) — hi-only f16 MFMA (K=192), R4-proven skeleton.
//
// reference:  anchor = mean(x[:,1:,:],1); pos = x[:,0,:]
//   logit[i,j] = -dist2 = s[i,j] + K_i,  s = 2*pos_i.anc_j + b_j,
//   b_j = -|anc_j|^2 + 2e*sum(anc_j).   K_i cancels in log_softmax/argmax.
//   nloss = mean(lse_i - s_ii), prec1 = 100*mean(argmax_j s == i).
//
// Precision: A = f16(2*log2e*pos), B = f16(anc), K=192 hi-only — VALIDATED
// R11 (passed, absmax 0.0).
// R11 post-mortem: __launch_bounds__(256,4) squeezed the unified reg file to
// 128/lane; acc=64 AGPRs left ~64 VGPRs for 48 regs of softmax state +
// fragments -> scratch spill, 446 MB/dispatch of phantom HBM traffic
// (WRITE_SIZE 278 MB vs 7 MB), 6% MfmaUtil.  Fix: (256,2) — the exact
// register environment of the measured-best R4 kernel (VGPR=100, no spill).

#define NROWS  8192
#define DDIM   192
#define KSPL   192            // hi-only
#define X3     576
#define FEPS   1e-6f
#define LOG2E  1.4426950408889634f
#define LN2    0.6931471805599453f

#define BM 128
#define BN 128
#define BK 64
#define NSPLIT 16
#define JRANGE 512            // NROWS / NSPLIT
#define JTILES 4              // JRANGE / BN
#define NPART  32             // NSPLIT * 2 (wn halves)
#define NCOMB  32             // combine-partial blocks

typedef _Float16 f16;
typedef _Float16 f16x4 __attribute__((ext_vector_type(4)));
typedef _Float16 f16x8 __attribute__((ext_vector_type(8)));
typedef float    f32x4 __attribute__((ext_vector_type(4)));

__device__ __forceinline__ void async_copy16(const void* g, void* l) {
  __builtin_amdgcn_global_load_lds(
      (const __attribute__((address_space(1))) unsigned int*)g,
      (__attribute__((address_space(3))) unsigned int*)l, 16, 0, 0);
}

// ---------- Kernel 1: x -> ph = f16(2*log2e*pos), ah = f16(anc), bvec -------
__global__ __launch_bounds__(256) void prep_kernel(const float* __restrict__ x,
                                                   f16* __restrict__ ph,
                                                   f16* __restrict__ ah,
                                                   float* __restrict__ bvec) {
  const int row  = (blockIdx.x * 256 + threadIdx.x) >> 6;
  const int lane = threadIdx.x & 63;
  float an = 0.f, as = 0.f;
  if (lane < 48) {
    const float* xr = x + (size_t)row * X3;
    const int d = lane * 4;
    const float4 p = *(const float4*)(xr + d);
    const float4 u = *(const float4*)(xr + DDIM + d);
    const float4 w = *(const float4*)(xr + 2 * DDIM + d);
    const float a0 = 0.5f * (u.x + w.x), a1 = 0.5f * (u.y + w.y);
    const float a2 = 0.5f * (u.z + w.z), a3 = 0.5f * (u.w + w.w);
    an = a0 * a0 + a1 * a1 + a2 * a2 + a3 * a3;
    as = a0 + a1 + a2 + a3;
    const float C2 = 2.0f * LOG2E;             // fold 2*log2e into A side
    f16x4 hv = {(f16)(p.x * C2), (f16)(p.y * C2), (f16)(p.z * C2), (f16)(p.w * C2)};
    *(f16x4*)(ph + (size_t)row * KSPL + d) = hv;
    f16x4 gv = {(f16)a0, (f16)a1, (f16)a2, (f16)a3};
    *(f16x4*)(ah + (size_t)row * KSPL + d) = gv;
  }
  #pragma unroll
  for (int m = 32; m; m >>= 1) {
    an += __shfl_xor(an, m);
    as += __shfl_xor(as, m);
  }
  if (lane == 0) bvec[row] = LOG2E * (-an + 2.0f * FEPS * as);  // log2-domain
}

// ---------- Kernel 2: f16 MFMA GEMM (K=192) + fused online LSE/argmax -------
// grid (64, 16) = 1024 blocks of 256 thr.  4 waves as 2x2; wave = 64x64 via
// 4x4 frags of mfma_f32_16x16x32_f16.  Single-buffer LDS (32 KB), R4-proven
// skeleton: [barrier; stage; barrier(drain); compute].  launch_bounds(256,2)
// = 256 unified regs/wave (no spill; R4 measured VGPR=100).
__global__ __launch_bounds__(256, 2) void main_kernel(
    const f16* __restrict__ Ag, const f16* __restrict__ Bg,
    const float* __restrict__ bvec,
    float* __restrict__ pm, float* __restrict__ ps, int* __restrict__ pa,
    float* __restrict__ diag) {
  __shared__ __align__(16) f16 As[BM * BK];   // 16 KB
  __shared__ __align__(16) f16 Bs[BN * BK];   // 16 KB
  const int tid  = threadIdx.x;
  const int lane = tid & 63;
  const int wid  = tid >> 6;
  const int wm = wid >> 1, wn = wid & 1;
  const int lLow = lane & 15, lHi = lane >> 4, l7 = lane & 7;
  const int i0 = blockIdx.x * BM;
  const int split = blockIdx.y;

  // staging: chunk ci = q*4+wid covers LDS rows [ci*8, ci*8+8); lane ->
  // (row = ci*8 + lane>>3, slot = lane&7); source k pre-swizzled so
  // LDS[row][slot] holds global k-chunk (slot ^ (row&7)).
  const int rsub = lane >> 3;
  const int srck = (l7 ^ rsub) * 8;

  float mrun[16], srun[16];
  int   arun[16];
  #pragma unroll
  for (int r = 0; r < 16; ++r) { mrun[r] = -3.0e38f; srun[r] = 0.f; arun[r] = 0; }

  for (int jt = 0; jt < JTILES; ++jt) {
    const int j0 = split * JRANGE + jt * BN;
    f32x4 acc[4][4];
    #pragma unroll
    for (int mf = 0; mf < 4; ++mf)
      #pragma unroll
      for (int nf = 0; nf < 4; ++nf) acc[mf][nf] = (f32x4)0.f;

    #pragma unroll
    for (int kc = 0; kc < KSPL; kc += BK) {
      __syncthreads();                 // previous tile fully consumed
      #pragma unroll
      for (int q = 0; q < 4; ++q) {
        const int ci  = q * 4 + wid;
        const int row = ci * 8 + rsub;
        async_copy16(Ag + (size_t)(i0 + row) * KSPL + kc + srck, (void*)(As + ci * 512));
        async_copy16(Bg + (size_t)(j0 + row) * KSPL + kc + srck, (void*)(Bs + ci * 512));
      }
      __syncthreads();                 // compiler drains vmcnt before barrier
      #pragma unroll
      for (int kk = 0; kk < 2; ++kk) {
        const int ksw = ((kk * 4 + lHi) ^ l7) * 8;  // swizzled read chunk
        f16x8 af[4];
        #pragma unroll
        for (int mf = 0; mf < 4; ++mf)
          af[mf] = *(const f16x8*)(As + (wm * 64 + mf * 16 + lLow) * 64 + ksw);
        #pragma unroll
        for (int nf = 0; nf < 4; ++nf) {
          f16x8 bf = *(const f16x8*)(Bs + (wn * 64 + nf * 16 + lLow) * 64 + ksw);
          #pragma unroll
          for (int mf = 0; mf < 4; ++mf)
            acc[mf][nf] = __builtin_amdgcn_mfma_f32_16x16x32_f16(af[mf], bf, acc[mf][nf], 0, 0, 0);
        }
      }
    }

    // ---- epilogue: fold this 128-wide j-tile into per-lane online state ----
    float bv[4];
    int   gc[4];
    #pragma unroll
    for (int nf = 0; nf < 4; ++nf) {
      gc[nf] = j0 + wn * 64 + nf * 16 + lLow;
      bv[nf] = bvec[gc[nf]];
    }
    // diagonal tile: j0 == i0  <=>  split*4 + jt == blockIdx.x
    const bool dtile = (split == (int)(blockIdx.x >> 2)) && (jt == (int)(blockIdx.x & 3));
    #pragma unroll
    for (int mf = 0; mf < 4; ++mf) {
      #pragma unroll
      for (int reg = 0; reg < 4; ++reg) {
        const int rs = mf * 4 + reg;
        const int grow = i0 + wm * 64 + mf * 16 + lHi * 4 + reg;
        float v0 = acc[mf][0][reg] + bv[0];   // log2-domain logits
        float v1 = acc[mf][1][reg] + bv[1];
        float v2 = acc[mf][2][reg] + bv[2];
        float v3 = acc[mf][3][reg] + bv[3];
        if (dtile) {
          if (grow == gc[0]) diag[grow] = v0;
          if (grow == gc[1]) diag[grow] = v1;
          if (grow == gc[2]) diag[grow] = v2;
          if (grow == gc[3]) diag[grow] = v3;
        }
        float tm = v0; int tj = gc[0];                // cols ascend with nf:
        if (v1 > tm) { tm = v1; tj = gc[1]; }         // strict > = first max
        if (v2 > tm) { tm = v2; tj = gc[2]; }
        if (v3 > tm) { tm = v3; tj = gc[3]; }
        float nm = fmaxf(tm, mrun[rs]);
        float se = exp2f(v0 - nm) + exp2f(v1 - nm) + exp2f(v2 - nm) + exp2f(v3 - nm);
        srun[rs] = srun[rs] * exp2f(mrun[rs] - nm) + se;
        if (tm > mrun[rs]) arun[rs] = tj;             // tie keeps earlier j
        mrun[rs] = nm;
      }
    }
  }

  // ---- reduce the 16 lanes sharing each row, write partials ----
  #pragma unroll
  for (int rs = 0; rs < 16; ++rs) {
    float mm = mrun[rs], ss = srun[rs];
    int aa = arun[rs];
    #pragma unroll
    for (int d = 1; d < 16; d <<= 1) {
      float om = __shfl_xor(mm, d, 16);
      float os = __shfl_xor(ss, d, 16);
      int   oa = __shfl_xor(aa, d, 16);
      float nm = fmaxf(mm, om);
      ss = ss * exp2f(mm - nm) + os * exp2f(om - nm);
      if (om > mm || (om == mm && oa < aa)) aa = oa;      // min-j on ties
      mm = nm;
    }
    if (lLow == 0) {
      const int grow = i0 + wm * 64 + (rs >> 2) * 16 + lHi * 4 + (rs & 3);
      const int sidx = split * 2 + wn;
      pm[(size_t)sidx * NROWS + grow] = mm;
      ps[(size_t)sidx * NROWS + grow] = ss;
      pa[(size_t)sidx * NROWS + grow] = aa;
    }
  }
}

// ---------- Kernel 3: merge partials per row (32 blocks, 1 row/thread) ------
__global__ __launch_bounds__(256) void combine_partial(
    const float* __restrict__ pm, const float* __restrict__ ps,
    const int* __restrict__ pa, const float* __restrict__ diag,
    float* __restrict__ partL, float* __restrict__ partC) {
  const int i = blockIdx.x * 256 + threadIdx.x;   // NCOMB*256 == NROWS
  float mm = pm[i];
  int   aa = pa[i];
  #pragma unroll
  for (int s = 1; s < NPART; ++s) {
    float om = pm[(size_t)s * NROWS + i];
    int   oa = pa[(size_t)s * NROWS + i];
    if (om > mm || (om == mm && oa < aa)) { mm = om; aa = oa; }
  }
  float ss = 0.f;
  #pragma unroll
  for (int s = 0; s < NPART; ++s)
    ss += ps[(size_t)s * NROWS + i] * exp2f(pm[(size_t)s * NROWS + i] - mm);
  float lsum = (mm + log2f(ss) - diag[i]) * LN2;  // back to nats
  float csum = (aa == i) ? 1.0f : 0.0f;
  #pragma unroll
  for (int d = 32; d; d >>= 1) {
    lsum += __shfl_xor(lsum, d);
    csum += __shfl_xor(csum, d);
  }
  __shared__ float wl[4], wc[4];
  int w = threadIdx.x >> 6;
  if ((threadIdx.x & 63) == 0) { wl[w] = lsum; wc[w] = csum; }
  __syncthreads();
  if (threadIdx.x == 0) {
    partL[blockIdx.x] = wl[0] + wl[1] + wl[2] + wl[3];
    partC[blockIdx.x] = wc[0] + wc[1] + wc[2] + wc[3];
  }
}

// ---------- Kernel 4: final scalars ----------
__global__ __launch_bounds__(64) void final_kernel(
    const float* __restrict__ partL, const float* __restrict__ partC,
    float* __restrict__ out) {
  int t = threadIdx.x;
  float l = (t < NCOMB) ? partL[t] : 0.f;
  float c = (t < NCOMB) ? partC[t] : 0.f;
  #pragma unroll
  for (int d = 32; d; d >>= 1) {
    l += __shfl_xor(l, d);
    c += __shfl_xor(c, d);
  }
  if (t == 0) {
    out[0] = l / (float)NROWS;
    out[1] = 100.f * c / (float)NROWS;
  }
}

extern "C" void kernel_launch(void* const* d_in, const int* in_sizes, int n_in,
                              void* d_out, int out_size, void* d_ws, size_t ws_size,
                              hipStream_t stream) {
  const float* x = (const float*)d_in[0];
  float* out = (float*)d_out;

  // workspace layout (~10.5 MB), 256B-aligned slices
  char* ws = (char*)d_ws;
  size_t off = 0;
  auto take = [&](size_t bytes) { void* p = ws + off; off += (bytes + 255) & ~(size_t)255; return p; };
  f16*   ph    = (f16*)take((size_t)NROWS * KSPL * sizeof(f16));
  f16*   ah    = (f16*)take((size_t)NROWS * KSPL * sizeof(f16));
  float* bvec  = (float*)take((size_t)NROWS * sizeof(float));
  float* pm    = (float*)take((size_t)NPART * NROWS * sizeof(float));
  float* ps    = (float*)take((size_t)NPART * NROWS * sizeof(float));
  int*   pa    = (int*)take((size_t)NPART * NROWS * sizeof(int));
  float* diag  = (float*)take((size_t)NROWS * sizeof(float));
  float* partL = (float*)take((size_t)NCOMB * sizeof(float));
  float* partC = (float*)take((size_t)NCOMB * sizeof(float));

  prep_kernel<<<dim3((NROWS * 64) / 256), 256, 0, stream>>>(x, ph, ah, bvec);
  main_kernel<<<dim3(NROWS / BM, NSPLIT), 256, 0, stream>>>(ph, ah, bvec, pm, ps, pa, diag);
  combine_partial<<<dim3(NCOMB), 256, 0, stream>>>(pm, ps, pa, diag, partL, partC);
  final_kernel<<<1, 64, 0, stream>>>(partL, partC, out);
}